// Round 9
// baseline (207.808 us; speedup 1.0000x reference)
//
#include <hip/hip_runtime.h>
#include <hip/hip_bf16.h>
#include <cstdint>

typedef _Float16 half2v __attribute__((ext_vector_type(2)));

#define EPB   16        // entities per bucket
#define MAXNB 1024      // max buckets for bin LDS histogram (NUMENT <= 16384)
#define FPB   8192      // facts per bin-block (1024 thr x FPT 8)
#define FPT   8         // facts per thread
#define SORTCAP 4608    // gather LDS payload capacity (u32 -> 18 KB)
#define CPT   9         // ceil(SORTCAP / 512) register-held entries per thread

// payload u32: [31:28]=local entity (4b) | [27:16]=rel (12b, R<4096) | [15:0]=fp16(val)

__device__ __forceinline__ float pay_val(unsigned p) {
    return (float)__builtin_bit_cast(_Float16, (unsigned short)(p & 0xFFFFu));
}

// ---------------------------------------------------------------------------
// Kernel 1: RWB[r][n] = dot(rel_features[r,:], W[n,:]) + b[n]   (fp16, [R][128])
// Also zeroes gcnt and out (fused memsets).
// ---------------------------------------------------------------------------
__global__ void rwb_row_kernel(const float* __restrict__ rel, const float* __restrict__ W,
                               const float* __restrict__ b, _Float16* __restrict__ rwb,
                               int R, int* __restrict__ gcnt, float* __restrict__ out,
                               int NB, int NUMENT) {
    const int k = blockIdx.x;        // relation index
    const int n = threadIdx.x;       // output feature (0..127)
    // fused zeroing (grid-strided)
    const int gtid = k * 128 + n;
    const int gstr = gridDim.x * 128;
    for (int i = gtid; i < NB; i += gstr) gcnt[i] = 0;
    const int n4 = NUMENT * 32;      // float4 count of out
    const float4 z = {0.f, 0.f, 0.f, 0.f};
    for (int i = gtid; i < n4; i += gstr)
        reinterpret_cast<float4*>(out)[i] = z;

    __shared__ float relk[128];
    relk[n] = rel[(size_t)k * 128 + n];
    __syncthreads();
    const float4* w4 = reinterpret_cast<const float4*>(W + (size_t)n * 128);
    const float4* r4 = reinterpret_cast<const float4*>(relk);
    float acc = 0.f;
#pragma unroll
    for (int i = 0; i < 32; ++i) {
        float4 a = r4[i], w = w4[i];
        acc += a.x * w.x + a.y * w.y + a.z * w.z + a.w * w.w;
    }
    rwb[(size_t)k * 128 + n] = (_Float16)(acc + b[n]);
}

// ---------------------------------------------------------------------------
// Spill path for bucket-capacity overflow (CAPB ~ mean + >9 sigma; guard only).
// ---------------------------------------------------------------------------
__device__ __noinline__ void spill_add(float* __restrict__ out, const _Float16* __restrict__ rwb,
                                       int v, unsigned pay) {
    const int r = (int)((pay >> 16) & 0xFFFu);
    const float val = pay_val(pay);
    float* o = out + (size_t)v * 128;
    const _Float16* rw = rwb + (size_t)r * 128;
    for (int n = 0; n < 128; ++n) unsafeAtomicAdd(o + n, val * (float)rw[n]);
}

// ---------------------------------------------------------------------------
// Kernel 2: bin endpoints into per-bucket lists (bucket = entity >> 4).
// UNCHANGED from round 8 (isolates the gather change).
// ---------------------------------------------------------------------------
__global__ __launch_bounds__(1024) void bin_kernel(
    const int* __restrict__ heads, const int* __restrict__ tails,
    const int* __restrict__ rels, const float* __restrict__ val,
    int* __restrict__ gcnt, unsigned* __restrict__ slots,
    const _Float16* __restrict__ rwb, float* __restrict__ out,
    int E, int NB, int CAPB) {
    __shared__ int cnt[MAXNB];
    __shared__ int gbase[MAXNB];
    const int t = threadIdx.x;
    for (int k = t; k < NB; k += 1024) cnt[k] = 0;
    __syncthreads();

    const int base = blockIdx.x * FPB;
    unsigned payT[FPT], payH[FPT], prT[FPT], prH[FPT];
#pragma unroll
    for (int u = 0; u < FPT; ++u) {
        const int i = base + u * 1024 + t;
        prT[u] = 0xFFFFFFFFu;
        prH[u] = 0xFFFFFFFFu;
        if (i < E) {
            const int tl = tails[i], hd = heads[i], r = rels[i];
            const unsigned hv =
                (unsigned)__builtin_bit_cast(unsigned short, (_Float16)val[i]);
            const int bt = tl >> 4, bh = hd >> 4;            // EPB = 16
            payT[u] = ((unsigned)(tl & 15) << 28) | ((unsigned)r << 16) | hv;
            payH[u] = ((unsigned)(hd & 15) << 28) | ((unsigned)r << 16) | hv;
            const int rt = atomicAdd(&cnt[bt], 1);           // LDS int rank (native)
            const int rh = atomicAdd(&cnt[bh], 1);
            prT[u] = ((unsigned)bt << 16) | (unsigned)rt;    // rank < 16384 fits
            prH[u] = ((unsigned)bh << 16) | (unsigned)rh;
        }
    }
    __syncthreads();
    for (int k = t; k < NB; k += 1024) {
        const int c = cnt[k];
        gbase[k] = c ? atomicAdd(&gcnt[k], c) : 0;           // 1 atomic / bucket / block
    }
    __syncthreads();
#pragma unroll
    for (int u = 0; u < FPT; ++u) {
        if (prT[u] != 0xFFFFFFFFu) {
            {
                const int b1 = (int)(prT[u] >> 16);
                const int pos = gbase[b1] + (int)(prT[u] & 0xFFFFu);
                if (pos < CAPB) slots[(size_t)b1 * CAPB + pos] = payT[u];
                else spill_add(out, rwb, (b1 << 4) | (int)(payT[u] >> 28), payT[u]);
            }
            {
                const int b1 = (int)(prH[u] >> 16);
                const int pos = gbase[b1] + (int)(prH[u] & 0xFFFFu);
                if (pos < CAPB) slots[(size_t)b1 * CAPB + pos] = payH[u];
                else spill_add(out, rwb, (b1 << 4) | (int)(payH[u] >> 28), payH[u]);
            }
        }
    }
}

// ---------------------------------------------------------------------------
// Kernel 3: one 512-thread block per 16-entity bucket.
// Phase A: counting sort into 18KB LDS; entity runs EVEN-PADDED (se pre-zeroed,
// zero payload => 0 * RWB[0] = 0).
// Phase B: split half-waves — lanes 0-31 process entry j, lanes 32-63 entry
// j+1. Each lane loads 8B (4 features) so one dwordx2 load fetches TWO rows;
// one per-lane-addressed ds_read_b32 fetches both payloads (2-way broadcast,
// free); readfirstlane eliminated (fma_mix takes VGPR payload f16 lo half).
// ~4.5 insts/entry vs round-8's ~6.5, memory-op count halved. Half-wave
// partials combined with __shfl_xor(.,32).
// ---------------------------------------------------------------------------
__global__ __launch_bounds__(512) void gather_kernel(
    const unsigned* __restrict__ slots, const int* __restrict__ gcnt,
    const _Float16* __restrict__ rwb, float* __restrict__ out,
    int NUMENT, int CAPB) {
    __shared__ unsigned se[SORTCAP];           // 18 KB sorted payloads (zeroed)
    __shared__ int cnt[EPB], basep[EPB];
    const int t = threadIdx.x;
    const int b = blockIdx.x;
    for (int k = t; k < SORTCAP; k += 512) se[k] = 0u;   // pad entries -> 0-add
    if (t < EPB) cnt[t] = 0;
    __syncthreads();

    int deg = gcnt[b];
    if (deg > CAPB) deg = CAPB;        // overflow entries were spilled by bin
    const unsigned* sl = slots + (size_t)b * CAPB;

    // Phase A: coalesced load, LDS rank, hold in registers, sorted placement
    unsigned e[CPT];
    int rk[CPT];
#pragma unroll
    for (int u = 0; u < CPT; ++u) {
        const int k = t + u * 512;
        rk[u] = -1;
        if (k < deg) {
            e[u] = sl[k];
            rk[u] = atomicAdd(&cnt[(int)(e[u] >> 28)], 1);
        }
    }
    __syncthreads();
    if (t == 0) {
        int s = 0;
#pragma unroll
        for (int i = 0; i < EPB; ++i) {
            basep[i] = s;
            s += (cnt[i] + 1) & ~1;            // even-padded runs (pads stay 0)
        }
    }
    __syncthreads();
#pragma unroll
    for (int u = 0; u < CPT; ++u)
        if (rk[u] >= 0) se[basep[(int)(e[u] >> 28)] + rk[u]] = e[u];
    __syncthreads();

    // Phase B: 8 waves x 2 entities; split half-wave pair processing
    const int wv = t >> 6, lane = t & 63;
    const int half = lane >> 5, l32 = lane & 31;
    const unsigned boff = (unsigned)l32 * 8u;  // byte offset within 256B row
    const char* rwbB = reinterpret_cast<const char*>(rwb);
#pragma unroll
    for (int ei = 0; ei < 2; ++ei) {
        const int le = wv * 2 + ei;
        const int vent = b * EPB + le;
        const int s0 = basep[le];
        const int cpad = (cnt[le] + 1) & ~1;
        float a0 = 0.f, a1 = 0.f, a2 = 0.f, a3 = 0.f;
        int j = 0;
        for (; j + 16 <= cpad; j += 16) {      // 8 pairs per iteration
            unsigned pay[8];
#pragma unroll
            for (int u = 0; u < 8; ++u) pay[u] = se[s0 + j + 2 * u + half];
            uint2 rw[8];
#pragma unroll
            for (int u = 0; u < 8; ++u) {
                const unsigned off = ((pay[u] >> 8) & 0xFFF00u) + boff; // rel*256+boff
                rw[u] = *reinterpret_cast<const uint2*>(rwbB + off);
            }
#pragma unroll
            for (int u = 0; u < 8; ++u) {
                asm("v_fma_mix_f32 %[d], %[p], %[r], %[d] op_sel:[0,0,0] op_sel_hi:[1,1,0]"
                    : [d]"+v"(a0) : [p]"v"(pay[u]), [r]"v"(rw[u].x));
                asm("v_fma_mix_f32 %[d], %[p], %[r], %[d] op_sel:[0,1,0] op_sel_hi:[1,1,0]"
                    : [d]"+v"(a1) : [p]"v"(pay[u]), [r]"v"(rw[u].x));
                asm("v_fma_mix_f32 %[d], %[p], %[r], %[d] op_sel:[0,0,0] op_sel_hi:[1,1,0]"
                    : [d]"+v"(a2) : [p]"v"(pay[u]), [r]"v"(rw[u].y));
                asm("v_fma_mix_f32 %[d], %[p], %[r], %[d] op_sel:[0,1,0] op_sel_hi:[1,1,0]"
                    : [d]"+v"(a3) : [p]"v"(pay[u]), [r]"v"(rw[u].y));
            }
        }
        for (; j < cpad; j += 2) {             // even-padded: full pairs only
            const unsigned pay = se[s0 + j + half];
            const unsigned off = ((pay >> 8) & 0xFFF00u) + boff;
            const uint2 rwv = *reinterpret_cast<const uint2*>(rwbB + off);
            asm("v_fma_mix_f32 %[d], %[p], %[r], %[d] op_sel:[0,0,0] op_sel_hi:[1,1,0]"
                : [d]"+v"(a0) : [p]"v"(pay), [r]"v"(rwv.x));
            asm("v_fma_mix_f32 %[d], %[p], %[r], %[d] op_sel:[0,1,0] op_sel_hi:[1,1,0]"
                : [d]"+v"(a1) : [p]"v"(pay), [r]"v"(rwv.x));
            asm("v_fma_mix_f32 %[d], %[p], %[r], %[d] op_sel:[0,0,0] op_sel_hi:[1,1,0]"
                : [d]"+v"(a2) : [p]"v"(pay), [r]"v"(rwv.y));
            asm("v_fma_mix_f32 %[d], %[p], %[r], %[d] op_sel:[0,1,0] op_sel_hi:[1,1,0]"
                : [d]"+v"(a3) : [p]"v"(pay), [r]"v"(rwv.y));
        }
        // combine half-wave partials: every lane ends with the full sum
        a0 += __shfl_xor(a0, 32);
        a1 += __shfl_xor(a1, 32);
        a2 += __shfl_xor(a2, 32);
        a3 += __shfl_xor(a3, 32);
        if (vent < NUMENT && half == 0) {
            float* op = out + (size_t)vent * 128 + l32 * 4;
            float4 sp = *reinterpret_cast<const float4*>(op);  // spill contrib (normally 0)
            float4 o;
            o.x = fmaxf(a0 + sp.x, 0.f);
            o.y = fmaxf(a1 + sp.y, 0.f);
            o.z = fmaxf(a2 + sp.z, 0.f);
            o.w = fmaxf(a3 + sp.w, 0.f);
            *reinterpret_cast<float4*>(op) = o;
        }
    }
}

// ---------------------------------------------------------------------------
// Fallback path (ws too small / shape out of range): direct vector scatter.
// ---------------------------------------------------------------------------
__global__ void rwb_f32_kernel(const float* __restrict__ rel, const float* __restrict__ W,
                               const float* __restrict__ b, float* __restrict__ rwb, int R) {
    const int k = blockIdx.x;
    const int n = threadIdx.x;
    __shared__ float relk[128];
    relk[n] = rel[(size_t)k * 128 + n];
    __syncthreads();
    const float4* w4 = reinterpret_cast<const float4*>(W + (size_t)n * 128);
    const float4* r4 = reinterpret_cast<const float4*>(relk);
    float acc = 0.f;
#pragma unroll
    for (int i = 0; i < 32; ++i) {
        float4 a = r4[i], w = w4[i];
        acc += a.x * w.x + a.y * w.y + a.z * w.z + a.w * w.w;
    }
    rwb[(size_t)k * 128 + n] = acc + b[n];
}

__global__ void scatter_vec_kernel(const int* __restrict__ heads, const int* __restrict__ tails,
                                   const int* __restrict__ rels, const float* __restrict__ val,
                                   const float* __restrict__ rwb, float* __restrict__ out,
                                   long long nitems) {
    const long long i = (long long)blockIdx.x * blockDim.x + threadIdx.x;
    if (i >= nitems) return;
    const int e = (int)(i >> 5);
    const int c = (int)(i & 31) * 4;
    const float v = val[e];
    float4 rw = *reinterpret_cast<const float4*>(rwb + (size_t)rels[e] * 128 + c);
    float* pt = out + (size_t)tails[e] * 128 + c;
    float* ph = out + (size_t)heads[e] * 128 + c;
    unsafeAtomicAdd(pt + 0, v * rw.x); unsafeAtomicAdd(pt + 1, v * rw.y);
    unsafeAtomicAdd(pt + 2, v * rw.z); unsafeAtomicAdd(pt + 3, v * rw.w);
    unsafeAtomicAdd(ph + 0, v * rw.x); unsafeAtomicAdd(ph + 1, v * rw.y);
    unsafeAtomicAdd(ph + 2, v * rw.z); unsafeAtomicAdd(ph + 3, v * rw.w);
}

__global__ void relu_kernel(float* __restrict__ out, int n4) {
    const int i = blockIdx.x * blockDim.x + threadIdx.x;
    if (i >= n4) return;
    float4* p = reinterpret_cast<float4*>(out) + i;
    float4 v = *p;
    v.x = fmaxf(v.x, 0.f); v.y = fmaxf(v.y, 0.f);
    v.z = fmaxf(v.z, 0.f); v.w = fmaxf(v.w, 0.f);
    *p = v;
}

// ---------------------------------------------------------------------------
extern "C" void kernel_launch(void* const* d_in, const int* in_sizes, int n_in,
                              void* d_out, int out_size, void* d_ws, size_t ws_size,
                              hipStream_t stream) {
    // inputs: 0 local_entity [B*M] (shape only), 1 heads [E], 2 tails [E],
    //         3 rels [E], 4 val [E], 5 rel_features [R*D], 6 W [D*D], 7 b [D]
    const int* heads = (const int*)d_in[1];
    const int* tails = (const int*)d_in[2];
    const int* rels  = (const int*)d_in[3];
    const float* val  = (const float*)d_in[4];
    const float* relf = (const float*)d_in[5];
    const float* W    = (const float*)d_in[6];
    const float* b    = (const float*)d_in[7];
    float* out = (float*)d_out;

    const int NUMENT = in_sizes[0];          // 16000
    const int E      = in_sizes[1];          // 2,000,000
    const int D      = in_sizes[7];          // 128
    const int R      = in_sizes[5] / D;      // 2000

    const int NB = (NUMENT + EPB - 1) / EPB; // 1000 buckets
    // expected endpoints/bucket = 2E*EPB/NUMENT (=4000, sigma~63);
    // slack mean/16+256 ~ +9.6 sigma at default shape
    const long long mean = (2LL * E * EPB) / (NUMENT > 0 ? NUMENT : 1);
    int CAPB = (int)(mean + mean / 16 + 256);

    const size_t rwb_bytes = (size_t)R * D * sizeof(_Float16);          // 512 KB
    const size_t off_gcnt  = (rwb_bytes + 255) & ~(size_t)255;
    const size_t gcnt_b    = (size_t)NB * sizeof(int);
    const size_t off_slots = (off_gcnt + gcnt_b + 255) & ~(size_t)255;
    const size_t slots_b   = (size_t)NB * CAPB * sizeof(unsigned);      // ~18 MB

    if (NB <= MAXNB && R < 4096 && CAPB <= SORTCAP - 2 * EPB &&   // even-pad headroom
        ws_size >= off_slots + slots_b) {
        _Float16* rwb   = (_Float16*)d_ws;
        int* gcnt       = (int*)((char*)d_ws + off_gcnt);
        unsigned* slots = (unsigned*)((char*)d_ws + off_slots);

        rwb_row_kernel<<<R, 128, 0, stream>>>(relf, W, b, rwb, R, gcnt, out, NB, NUMENT);
        bin_kernel<<<(E + FPB - 1) / FPB, 1024, 0, stream>>>(
            heads, tails, rels, val, gcnt, slots, rwb, out, E, NB, CAPB);
        gather_kernel<<<NB, 512, 0, stream>>>(slots, gcnt, rwb, out, NUMENT, CAPB);
    } else {
        // fallback: accumulate directly into out (slow but small-ws safe)
        float* rwb = (float*)d_ws;           // R*D fp32 (~1 MB)
        hipMemsetAsync(out, 0, (size_t)out_size * sizeof(float), stream);
        rwb_f32_kernel<<<R, 128, 0, stream>>>(relf, W, b, rwb, R);
        const long long items = (long long)E * 32;
        scatter_vec_kernel<<<(unsigned)((items + 255) / 256), 256, 0, stream>>>(
            heads, tails, rels, val, rwb, out, items);
        relu_kernel<<<(out_size / 4 + 255) / 256, 256, 0, stream>>>(out, out_size / 4);
    }
}

// Round 10
// 202.200 us; speedup vs baseline: 1.0277x; 1.0277x over previous
//
#include <hip/hip_runtime.h>
#include <hip/hip_bf16.h>
#include <cstdint>

typedef _Float16 half2v __attribute__((ext_vector_type(2)));

#define EPB   16        // entities per bucket
#define MAXNB 1024      // max buckets for bin LDS histogram (NUMENT <= 16384)
#define FPB   4096      // facts per bin-block (1024 thr x FPT 4) -> 489 blocks (~2/CU)
#define FPT   4         // facts per thread
#define SORTCAP 4608    // gather LDS payload capacity (u32 -> 18 KB)
#define CPT   9         // ceil(SORTCAP / 512) register-held entries per thread

// payload u32: [31:28]=local entity (4b) | [27:16]=rel (12b, R<4096) | [15:0]=fp16(val)

__device__ __forceinline__ float pay_val(unsigned p) {
    return (float)__builtin_bit_cast(_Float16, (unsigned short)(p & 0xFFFFu));
}

// ---------------------------------------------------------------------------
// Kernel 1: RWB[r][n] = dot(rel_features[r,:], W[n,:]) + b[n]   (fp16, [R][128])
// Also zeroes gcnt and out (fused memsets).
// ---------------------------------------------------------------------------
__global__ void rwb_row_kernel(const float* __restrict__ rel, const float* __restrict__ W,
                               const float* __restrict__ b, _Float16* __restrict__ rwb,
                               int R, int* __restrict__ gcnt, float* __restrict__ out,
                               int NB, int NUMENT) {
    const int k = blockIdx.x;        // relation index
    const int n = threadIdx.x;       // output feature (0..127)
    // fused zeroing (grid-strided)
    const int gtid = k * 128 + n;
    const int gstr = gridDim.x * 128;
    for (int i = gtid; i < NB; i += gstr) gcnt[i] = 0;
    const int n4 = NUMENT * 32;      // float4 count of out
    const float4 z = {0.f, 0.f, 0.f, 0.f};
    for (int i = gtid; i < n4; i += gstr)
        reinterpret_cast<float4*>(out)[i] = z;

    __shared__ float relk[128];
    relk[n] = rel[(size_t)k * 128 + n];
    __syncthreads();
    const float4* w4 = reinterpret_cast<const float4*>(W + (size_t)n * 128);
    const float4* r4 = reinterpret_cast<const float4*>(relk);
    float acc = 0.f;
#pragma unroll
    for (int i = 0; i < 32; ++i) {
        float4 a = r4[i], w = w4[i];
        acc += a.x * w.x + a.y * w.y + a.z * w.z + a.w * w.w;
    }
    rwb[(size_t)k * 128 + n] = (_Float16)(acc + b[n]);
}

// ---------------------------------------------------------------------------
// Spill path for bucket-capacity overflow (CAPB ~ mean + >9 sigma; guard only).
// ---------------------------------------------------------------------------
__device__ __noinline__ void spill_add(float* __restrict__ out, const _Float16* __restrict__ rwb,
                                       int v, unsigned pay) {
    const int r = (int)((pay >> 16) & 0xFFFu);
    const float val = pay_val(pay);
    float* o = out + (size_t)v * 128;
    const _Float16* rw = rwb + (size_t)r * 128;
    for (int n = 0; n < 128; ++n) unsafeAtomicAdd(o + n, val * (float)rw[n]);
}

// ---------------------------------------------------------------------------
// Kernel 2: bin endpoints into per-bucket lists (bucket = entity >> 4).
// FPT 8 -> 4: grid 245 -> 489 blocks (~2/CU; 245 left 11 CUs idle and gave no
// block-level overlap for the latency-bound LDS-atomic + scattered-store mix).
// ---------------------------------------------------------------------------
__global__ __launch_bounds__(1024) void bin_kernel(
    const int* __restrict__ heads, const int* __restrict__ tails,
    const int* __restrict__ rels, const float* __restrict__ val,
    int* __restrict__ gcnt, unsigned* __restrict__ slots,
    const _Float16* __restrict__ rwb, float* __restrict__ out,
    int E, int NB, int CAPB) {
    __shared__ int cnt[MAXNB];
    __shared__ int gbase[MAXNB];
    const int t = threadIdx.x;
    for (int k = t; k < NB; k += 1024) cnt[k] = 0;
    __syncthreads();

    const int base = blockIdx.x * FPB;
    unsigned payT[FPT], payH[FPT], prT[FPT], prH[FPT];
#pragma unroll
    for (int u = 0; u < FPT; ++u) {
        const int i = base + u * 1024 + t;
        prT[u] = 0xFFFFFFFFu;
        prH[u] = 0xFFFFFFFFu;
        if (i < E) {
            const int tl = tails[i], hd = heads[i], r = rels[i];
            const unsigned hv =
                (unsigned)__builtin_bit_cast(unsigned short, (_Float16)val[i]);
            const int bt = tl >> 4, bh = hd >> 4;            // EPB = 16
            payT[u] = ((unsigned)(tl & 15) << 28) | ((unsigned)r << 16) | hv;
            payH[u] = ((unsigned)(hd & 15) << 28) | ((unsigned)r << 16) | hv;
            const int rt = atomicAdd(&cnt[bt], 1);           // LDS int rank (native)
            const int rh = atomicAdd(&cnt[bh], 1);
            prT[u] = ((unsigned)bt << 16) | (unsigned)rt;    // rank < 16384 fits
            prH[u] = ((unsigned)bh << 16) | (unsigned)rh;
        }
    }
    __syncthreads();
    for (int k = t; k < NB; k += 1024) {
        const int c = cnt[k];
        gbase[k] = c ? atomicAdd(&gcnt[k], c) : 0;           // 1 atomic / bucket / block
    }
    __syncthreads();
#pragma unroll
    for (int u = 0; u < FPT; ++u) {
        if (prT[u] != 0xFFFFFFFFu) {
            {
                const int b1 = (int)(prT[u] >> 16);
                const int pos = gbase[b1] + (int)(prT[u] & 0xFFFFu);
                if (pos < CAPB) slots[(size_t)b1 * CAPB + pos] = payT[u];
                else spill_add(out, rwb, (b1 << 4) | (int)(payT[u] >> 28), payT[u]);
            }
            {
                const int b1 = (int)(prH[u] >> 16);
                const int pos = gbase[b1] + (int)(prH[u] & 0xFFFFu);
                if (pos < CAPB) slots[(size_t)b1 * CAPB + pos] = payH[u];
                else spill_add(out, rwb, (b1 << 4) | (int)(payH[u] >> 28), payH[u]);
            }
        }
    }
}

// ---------------------------------------------------------------------------
// Kernel 3: one 512-thread block per 16-entity bucket.
// Phase A: counting sort into 18KB LDS (round-8 structure, no padding).
// Phase B: round-8's scalarized loop (ds_read broadcast -> readfirstlane ->
// saddr row load -> 2x v_fma_mix_f32), now 2-STAGE SOFTWARE PIPELINED:
// batch j+8's payloads are ds_read AND its row loads issued before batch j's
// FMAs, hiding the serial ds->rfl->load chain (~320cy) under compute + TLP.
// (Round-9's pair-processing variant regressed: per-lane vector addressing
// added more VALU than the readfirstlane it removed. Reverted.)
// ---------------------------------------------------------------------------
__global__ __launch_bounds__(512) void gather_kernel(
    const unsigned* __restrict__ slots, const int* __restrict__ gcnt,
    const _Float16* __restrict__ rwb, float* __restrict__ out,
    int NUMENT, int CAPB) {
    __shared__ unsigned se[SORTCAP];           // 18 KB sorted payloads
    __shared__ int cnt[EPB], basep[EPB];
    const int t = threadIdx.x;
    const int b = blockIdx.x;
    if (t < EPB) cnt[t] = 0;
    __syncthreads();

    int deg = gcnt[b];
    if (deg > CAPB) deg = CAPB;        // overflow entries were spilled by bin
    const unsigned* sl = slots + (size_t)b * CAPB;

    // Phase A: coalesced load, LDS rank, hold in registers, sorted placement
    unsigned e[CPT];
    int rk[CPT];
#pragma unroll
    for (int u = 0; u < CPT; ++u) {
        const int k = t + u * 512;
        rk[u] = -1;
        if (k < deg) {
            e[u] = sl[k];
            rk[u] = atomicAdd(&cnt[(int)(e[u] >> 28)], 1);
        }
    }
    __syncthreads();
    if (t == 0) {
        int s = 0;
#pragma unroll
        for (int i = 0; i < EPB; ++i) { basep[i] = s; s += cnt[i]; }
    }
    __syncthreads();
#pragma unroll
    for (int u = 0; u < CPT; ++u)
        if (rk[u] >= 0) se[basep[(int)(e[u] >> 28)] + rk[u]] = e[u];
    __syncthreads();

    // Phase B: 8 waves x 2 entities, 2-stage pipelined batches of 8
    const int wv = t >> 6, lane = t & 63;
    const int loff = lane * 2;                 // _Float16 element offset in row
#pragma unroll
    for (int ei = 0; ei < 2; ++ei) {
        const int le = wv * 2 + ei;
        const int vent = b * EPB + le;
        const int s0 = basep[le], c = cnt[le];
        float a0 = 0.f, a1 = 0.f;
        int j = 0;
        if (c >= 8) {
            unsigned q[8], qs[8], rw[8];
#pragma unroll
            for (int u = 0; u < 8; ++u) q[u] = se[s0 + u];
#pragma unroll
            for (int u = 0; u < 8; ++u) qs[u] = __builtin_amdgcn_readfirstlane(q[u]);
#pragma unroll
            for (int u = 0; u < 8; ++u) {
                const _Float16* rowp = rwb + (size_t)((qs[u] >> 16) & 0xFFFu) * 128;
                rw[u] = *reinterpret_cast<const unsigned*>(rowp + loff);
            }
            for (; j + 16 <= c; j += 8) {
                unsigned qn[8], qsn[8], rwn[8];
#pragma unroll
                for (int u = 0; u < 8; ++u) qn[u] = se[s0 + j + 8 + u];  // prefetch DS
#pragma unroll
                for (int u = 0; u < 8; ++u) qsn[u] = __builtin_amdgcn_readfirstlane(qn[u]);
#pragma unroll
                for (int u = 0; u < 8; ++u) {                            // prefetch rows
                    const _Float16* rowp = rwb + (size_t)((qsn[u] >> 16) & 0xFFFu) * 128;
                    rwn[u] = *reinterpret_cast<const unsigned*>(rowp + loff);
                }
#pragma unroll
                for (int u = 0; u < 8; ++u) {                            // compute current
                    asm("v_fma_mix_f32 %[d], %[s0], %[s1], %[d] op_sel:[0,0,0] op_sel_hi:[1,1,0]"
                        : [d]"+v"(a0) : [s0]"s"(qs[u]), [s1]"v"(rw[u]));
                    asm("v_fma_mix_f32 %[d], %[s0], %[s1], %[d] op_sel:[0,1,0] op_sel_hi:[1,1,0]"
                        : [d]"+v"(a1) : [s0]"s"(qs[u]), [s1]"v"(rw[u]));
                }
#pragma unroll
                for (int u = 0; u < 8; ++u) { qs[u] = qsn[u]; rw[u] = rwn[u]; }
            }
            // drain the in-flight batch
#pragma unroll
            for (int u = 0; u < 8; ++u) {
                asm("v_fma_mix_f32 %[d], %[s0], %[s1], %[d] op_sel:[0,0,0] op_sel_hi:[1,1,0]"
                    : [d]"+v"(a0) : [s0]"s"(qs[u]), [s1]"v"(rw[u]));
                asm("v_fma_mix_f32 %[d], %[s0], %[s1], %[d] op_sel:[0,1,0] op_sel_hi:[1,1,0]"
                    : [d]"+v"(a1) : [s0]"s"(qs[u]), [s1]"v"(rw[u]));
            }
            j += 8;
        }
        for (; j < c; ++j) {
            const unsigned q = se[s0 + j];
            const unsigned qs = __builtin_amdgcn_readfirstlane(q);
            const _Float16* rowp = rwb + (size_t)((qs >> 16) & 0xFFFu) * 128;
            const unsigned rwv = *reinterpret_cast<const unsigned*>(rowp + loff);
            asm("v_fma_mix_f32 %[d], %[s0], %[s1], %[d] op_sel:[0,0,0] op_sel_hi:[1,1,0]"
                : [d]"+v"(a0) : [s0]"s"(qs), [s1]"v"(rwv));
            asm("v_fma_mix_f32 %[d], %[s0], %[s1], %[d] op_sel:[0,1,0] op_sel_hi:[1,1,0]"
                : [d]"+v"(a1) : [s0]"s"(qs), [s1]"v"(rwv));
        }
        if (vent < NUMENT) {
            float* op = out + (size_t)vent * 128 + loff;
            float2 sp = *reinterpret_cast<const float2*>(op);  // spill contrib (normally 0)
            float2 o;
            o.x = fmaxf(a0 + sp.x, 0.f);
            o.y = fmaxf(a1 + sp.y, 0.f);
            *reinterpret_cast<float2*>(op) = o;
        }
    }
}

// ---------------------------------------------------------------------------
// Fallback path (ws too small / shape out of range): direct vector scatter.
// ---------------------------------------------------------------------------
__global__ void rwb_f32_kernel(const float* __restrict__ rel, const float* __restrict__ W,
                               const float* __restrict__ b, float* __restrict__ rwb, int R) {
    const int k = blockIdx.x;
    const int n = threadIdx.x;
    __shared__ float relk[128];
    relk[n] = rel[(size_t)k * 128 + n];
    __syncthreads();
    const float4* w4 = reinterpret_cast<const float4*>(W + (size_t)n * 128);
    const float4* r4 = reinterpret_cast<const float4*>(relk);
    float acc = 0.f;
#pragma unroll
    for (int i = 0; i < 32; ++i) {
        float4 a = r4[i], w = w4[i];
        acc += a.x * w.x + a.y * w.y + a.z * w.z + a.w * w.w;
    }
    rwb[(size_t)k * 128 + n] = acc + b[n];
}

__global__ void scatter_vec_kernel(const int* __restrict__ heads, const int* __restrict__ tails,
                                   const int* __restrict__ rels, const float* __restrict__ val,
                                   const float* __restrict__ rwb, float* __restrict__ out,
                                   long long nitems) {
    const long long i = (long long)blockIdx.x * blockDim.x + threadIdx.x;
    if (i >= nitems) return;
    const int e = (int)(i >> 5);
    const int c = (int)(i & 31) * 4;
    const float v = val[e];
    float4 rw = *reinterpret_cast<const float4*>(rwb + (size_t)rels[e] * 128 + c);
    float* pt = out + (size_t)tails[e] * 128 + c;
    float* ph = out + (size_t)heads[e] * 128 + c;
    unsafeAtomicAdd(pt + 0, v * rw.x); unsafeAtomicAdd(pt + 1, v * rw.y);
    unsafeAtomicAdd(pt + 2, v * rw.z); unsafeAtomicAdd(pt + 3, v * rw.w);
    unsafeAtomicAdd(ph + 0, v * rw.x); unsafeAtomicAdd(ph + 1, v * rw.y);
    unsafeAtomicAdd(ph + 2, v * rw.z); unsafeAtomicAdd(ph + 3, v * rw.w);
}

__global__ void relu_kernel(float* __restrict__ out, int n4) {
    const int i = blockIdx.x * blockDim.x + threadIdx.x;
    if (i >= n4) return;
    float4* p = reinterpret_cast<float4*>(out) + i;
    float4 v = *p;
    v.x = fmaxf(v.x, 0.f); v.y = fmaxf(v.y, 0.f);
    v.z = fmaxf(v.z, 0.f); v.w = fmaxf(v.w, 0.f);
    *p = v;
}

// ---------------------------------------------------------------------------
extern "C" void kernel_launch(void* const* d_in, const int* in_sizes, int n_in,
                              void* d_out, int out_size, void* d_ws, size_t ws_size,
                              hipStream_t stream) {
    // inputs: 0 local_entity [B*M] (shape only), 1 heads [E], 2 tails [E],
    //         3 rels [E], 4 val [E], 5 rel_features [R*D], 6 W [D*D], 7 b [D]
    const int* heads = (const int*)d_in[1];
    const int* tails = (const int*)d_in[2];
    const int* rels  = (const int*)d_in[3];
    const float* val  = (const float*)d_in[4];
    const float* relf = (const float*)d_in[5];
    const float* W    = (const float*)d_in[6];
    const float* b    = (const float*)d_in[7];
    float* out = (float*)d_out;

    const int NUMENT = in_sizes[0];          // 16000
    const int E      = in_sizes[1];          // 2,000,000
    const int D      = in_sizes[7];          // 128
    const int R      = in_sizes[5] / D;      // 2000

    const int NB = (NUMENT + EPB - 1) / EPB; // 1000 buckets
    // expected endpoints/bucket = 2E*EPB/NUMENT (=4000, sigma~63);
    // slack mean/16+256 ~ +9.6 sigma at default shape
    const long long mean = (2LL * E * EPB) / (NUMENT > 0 ? NUMENT : 1);
    int CAPB = (int)(mean + mean / 16 + 256);

    const size_t rwb_bytes = (size_t)R * D * sizeof(_Float16);          // 512 KB
    const size_t off_gcnt  = (rwb_bytes + 255) & ~(size_t)255;
    const size_t gcnt_b    = (size_t)NB * sizeof(int);
    const size_t off_slots = (off_gcnt + gcnt_b + 255) & ~(size_t)255;
    const size_t slots_b   = (size_t)NB * CAPB * sizeof(unsigned);      // ~18 MB

    if (NB <= MAXNB && R < 4096 && CAPB <= SORTCAP &&
        ws_size >= off_slots + slots_b) {
        _Float16* rwb   = (_Float16*)d_ws;
        int* gcnt       = (int*)((char*)d_ws + off_gcnt);
        unsigned* slots = (unsigned*)((char*)d_ws + off_slots);

        rwb_row_kernel<<<R, 128, 0, stream>>>(relf, W, b, rwb, R, gcnt, out, NB, NUMENT);
        bin_kernel<<<(E + FPB - 1) / FPB, 1024, 0, stream>>>(
            heads, tails, rels, val, gcnt, slots, rwb, out, E, NB, CAPB);
        gather_kernel<<<NB, 512, 0, stream>>>(slots, gcnt, rwb, out, NUMENT, CAPB);
    } else {
        // fallback: accumulate directly into out (slow but small-ws safe)
        float* rwb = (float*)d_ws;           // R*D fp32 (~1 MB)
        hipMemsetAsync(out, 0, (size_t)out_size * sizeof(float), stream);
        rwb_f32_kernel<<<R, 128, 0, stream>>>(relf, W, b, rwb, R);
        const long long items = (long long)E * 32;
        scatter_vec_kernel<<<(unsigned)((items + 255) / 256), 256, 0, stream>>>(
            heads, tails, rels, val, rwb, out, items);
        relu_kernel<<<(out_size / 4 + 255) / 256, 256, 0, stream>>>(out, out_size / 4);
    }
}

// Round 11
// 188.389 us; speedup vs baseline: 1.1031x; 1.0733x over previous
//
#include <hip/hip_runtime.h>
#include <hip/hip_bf16.h>
#include <cstdint>

typedef _Float16 half2v __attribute__((ext_vector_type(2)));

#define EPB   16        // entities per bucket
#define MAXNB 1024      // max buckets for bin LDS histogram (NUMENT <= 16384)
#define FPB   4096      // facts per bin-block (1024 thr x FPT 4) -> 489 blocks (~2/CU)
#define FPT   4         // facts per thread (CONSECUTIVE -> dwordx4 loads)
#define SORTCAP 4608    // gather LDS payload capacity (u32 -> 18 KB)
#define CPT   9         // ceil(SORTCAP / 512) register-held entries per thread

// payload u32: [31:28]=local entity (4b) | [27:16]=rel (12b, R<4096) | [15:0]=fp16(val)

__device__ __forceinline__ float pay_val(unsigned p) {
    return (float)__builtin_bit_cast(_Float16, (unsigned short)(p & 0xFFFFu));
}

// ---------------------------------------------------------------------------
// Kernel 1: RWB[r][n] = dot(rel_features[r,:], W[n,:]) + b[n]   (fp16, [R][128])
// Also zeroes gcnt and out (fused memsets).
// ---------------------------------------------------------------------------
__global__ void rwb_row_kernel(const float* __restrict__ rel, const float* __restrict__ W,
                               const float* __restrict__ b, _Float16* __restrict__ rwb,
                               int R, int* __restrict__ gcnt, float* __restrict__ out,
                               int NB, int NUMENT) {
    const int k = blockIdx.x;        // relation index
    const int n = threadIdx.x;       // output feature (0..127)
    // fused zeroing (grid-strided)
    const int gtid = k * 128 + n;
    const int gstr = gridDim.x * 128;
    for (int i = gtid; i < NB; i += gstr) gcnt[i] = 0;
    const int n4 = NUMENT * 32;      // float4 count of out
    const float4 z = {0.f, 0.f, 0.f, 0.f};
    for (int i = gtid; i < n4; i += gstr)
        reinterpret_cast<float4*>(out)[i] = z;

    __shared__ float relk[128];
    relk[n] = rel[(size_t)k * 128 + n];
    __syncthreads();
    const float4* w4 = reinterpret_cast<const float4*>(W + (size_t)n * 128);
    const float4* r4 = reinterpret_cast<const float4*>(relk);
    float acc = 0.f;
#pragma unroll
    for (int i = 0; i < 32; ++i) {
        float4 a = r4[i], w = w4[i];
        acc += a.x * w.x + a.y * w.y + a.z * w.z + a.w * w.w;
    }
    rwb[(size_t)k * 128 + n] = (_Float16)(acc + b[n]);
}

// ---------------------------------------------------------------------------
// Spill path for bucket-capacity overflow (CAPB ~ mean + >9 sigma; guard only).
// ---------------------------------------------------------------------------
__device__ __noinline__ void spill_add(float* __restrict__ out, const _Float16* __restrict__ rwb,
                                       int v, unsigned pay) {
    const int r = (int)((pay >> 16) & 0xFFFu);
    const float val = pay_val(pay);
    float* o = out + (size_t)v * 128;
    const _Float16* rw = rwb + (size_t)r * 128;
    for (int n = 0; n < 128; ++n) unsafeAtomicAdd(o + n, val * (float)rw[n]);
}

// ---------------------------------------------------------------------------
// Kernel 2: bin endpoints into per-bucket lists (bucket = entity >> 4).
// Each thread now owns 4 CONSECUTIVE facts -> dwordx4/float4 loads: 16 scalar
// dword VMEM issues/thread -> 4. Same bytes, same coalescing, same run-length
// profile; rank order within block changes (commutative sum, tolerance-safe).
// ---------------------------------------------------------------------------
__global__ __launch_bounds__(1024) void bin_kernel(
    const int* __restrict__ heads, const int* __restrict__ tails,
    const int* __restrict__ rels, const float* __restrict__ val,
    int* __restrict__ gcnt, unsigned* __restrict__ slots,
    const _Float16* __restrict__ rwb, float* __restrict__ out,
    int E, int NB, int CAPB) {
    __shared__ int cnt[MAXNB];
    __shared__ int gbase[MAXNB];
    const int t = threadIdx.x;
    for (int k = t; k < NB; k += 1024) cnt[k] = 0;
    __syncthreads();

    const int i0 = blockIdx.x * FPB + t * FPT;
    unsigned payT[FPT], payH[FPT], prT[FPT], prH[FPT];
#pragma unroll
    for (int u = 0; u < FPT; ++u) { prT[u] = 0xFFFFFFFFu; prH[u] = 0xFFFFFFFFu; }

    int tl[FPT], hd[FPT], rr[FPT];
    float vv[FPT];
    int nval = 0;
    if (i0 + FPT <= E) {
        const int4 T  = *reinterpret_cast<const int4*>(tails + i0);
        const int4 H  = *reinterpret_cast<const int4*>(heads + i0);
        const int4 Rv = *reinterpret_cast<const int4*>(rels + i0);
        const float4 Vv = *reinterpret_cast<const float4*>(val + i0);
        tl[0] = T.x;  tl[1] = T.y;  tl[2] = T.z;  tl[3] = T.w;
        hd[0] = H.x;  hd[1] = H.y;  hd[2] = H.z;  hd[3] = H.w;
        rr[0] = Rv.x; rr[1] = Rv.y; rr[2] = Rv.z; rr[3] = Rv.w;
        vv[0] = Vv.x; vv[1] = Vv.y; vv[2] = Vv.z; vv[3] = Vv.w;
        nval = FPT;
    } else {
#pragma unroll
        for (int u = 0; u < FPT; ++u) {
            const int i = i0 + u;
            if (i < E) {
                tl[u] = tails[i]; hd[u] = heads[i];
                rr[u] = rels[i];  vv[u] = val[i];
                nval = u + 1;
            }
        }
    }
#pragma unroll
    for (int u = 0; u < FPT; ++u) {
        if (u < nval) {
            const unsigned hv =
                (unsigned)__builtin_bit_cast(unsigned short, (_Float16)vv[u]);
            const int bt = tl[u] >> 4, bh = hd[u] >> 4;      // EPB = 16
            payT[u] = ((unsigned)(tl[u] & 15) << 28) | ((unsigned)rr[u] << 16) | hv;
            payH[u] = ((unsigned)(hd[u] & 15) << 28) | ((unsigned)rr[u] << 16) | hv;
            const int rt = atomicAdd(&cnt[bt], 1);           // LDS int rank (native)
            const int rh = atomicAdd(&cnt[bh], 1);
            prT[u] = ((unsigned)bt << 16) | (unsigned)rt;    // rank < 16384 fits
            prH[u] = ((unsigned)bh << 16) | (unsigned)rh;
        }
    }
    __syncthreads();
    for (int k = t; k < NB; k += 1024) {
        const int c = cnt[k];
        gbase[k] = c ? atomicAdd(&gcnt[k], c) : 0;           // 1 atomic / bucket / block
    }
    __syncthreads();
#pragma unroll
    for (int u = 0; u < FPT; ++u) {
        if (prT[u] != 0xFFFFFFFFu) {
            {
                const int b1 = (int)(prT[u] >> 16);
                const int pos = gbase[b1] + (int)(prT[u] & 0xFFFFu);
                if (pos < CAPB) slots[(size_t)b1 * CAPB + pos] = payT[u];
                else spill_add(out, rwb, (b1 << 4) | (int)(payT[u] >> 28), payT[u]);
            }
            {
                const int b1 = (int)(prH[u] >> 16);
                const int pos = gbase[b1] + (int)(prH[u] & 0xFFFFu);
                if (pos < CAPB) slots[(size_t)b1 * CAPB + pos] = payH[u];
                else spill_add(out, rwb, (b1 << 4) | (int)(payH[u] >> 28), payH[u]);
            }
        }
    }
}

// ---------------------------------------------------------------------------
// Kernel 3: one 512-thread block per 16-entity bucket.
// Phase A: counting sort into 18KB LDS (round-8 structure).
// Phase B: round-8's EXACT scalarized loop (proven 62us; r9/r10 pipelining
// variants both regressed by adding issue slots), with ONE change: payloads
// read as uint2 -> ds_read2_b32, halving DS issues (1 per 2 entries).
// ---------------------------------------------------------------------------
__global__ __launch_bounds__(512) void gather_kernel(
    const unsigned* __restrict__ slots, const int* __restrict__ gcnt,
    const _Float16* __restrict__ rwb, float* __restrict__ out,
    int NUMENT, int CAPB) {
    __shared__ unsigned se[SORTCAP];           // 18 KB sorted payloads
    __shared__ int cnt[EPB], basep[EPB];
    const int t = threadIdx.x;
    const int b = blockIdx.x;
    if (t < EPB) cnt[t] = 0;
    __syncthreads();

    int deg = gcnt[b];
    if (deg > CAPB) deg = CAPB;        // overflow entries were spilled by bin
    const unsigned* sl = slots + (size_t)b * CAPB;

    // Phase A: coalesced load, LDS rank, hold in registers, sorted placement
    unsigned e[CPT];
    int rk[CPT];
#pragma unroll
    for (int u = 0; u < CPT; ++u) {
        const int k = t + u * 512;
        rk[u] = -1;
        if (k < deg) {
            e[u] = sl[k];
            rk[u] = atomicAdd(&cnt[(int)(e[u] >> 28)], 1);
        }
    }
    __syncthreads();
    if (t == 0) {
        int s = 0;
#pragma unroll
        for (int i = 0; i < EPB; ++i) { basep[i] = s; s += cnt[i]; }
    }
    __syncthreads();
#pragma unroll
    for (int u = 0; u < CPT; ++u)
        if (rk[u] >= 0) se[basep[(int)(e[u] >> 28)] + rk[u]] = e[u];
    __syncthreads();

    // Phase B: 8 waves x 2 entities; scalarized, batches of 8
    const int wv = t >> 6, lane = t & 63;
    const int loff = lane * 2;                 // _Float16 element offset in row
#pragma unroll
    for (int ei = 0; ei < 2; ++ei) {
        const int le = wv * 2 + ei;
        const int vent = b * EPB + le;
        const int s0 = basep[le], c = cnt[le];
        float a0 = 0.f, a1 = 0.f;
        int j = 0;
        for (; j + 8 <= c; j += 8) {
            uint2 qp[4];
#pragma unroll
            for (int u = 0; u < 4; ++u)        // ds_read2_b32: 2 payloads / issue
                qp[u] = *reinterpret_cast<const uint2*>(&se[s0 + j + 2 * u]);
            unsigned qs[8];
#pragma unroll
            for (int u = 0; u < 4; ++u) {
                qs[2 * u]     = __builtin_amdgcn_readfirstlane(qp[u].x);
                qs[2 * u + 1] = __builtin_amdgcn_readfirstlane(qp[u].y);
            }
            unsigned rw[8];
#pragma unroll
            for (int u = 0; u < 8; ++u) {
                const _Float16* rowp = rwb + (size_t)((qs[u] >> 16) & 0xFFFu) * 128;
                rw[u] = *reinterpret_cast<const unsigned*>(rowp + loff);  // saddr + v_lane
            }
#pragma unroll
            for (int u = 0; u < 8; ++u) {
                asm("v_fma_mix_f32 %[d], %[s0], %[s1], %[d] op_sel:[0,0,0] op_sel_hi:[1,1,0]"
                    : [d]"+v"(a0) : [s0]"s"(qs[u]), [s1]"v"(rw[u]));
                asm("v_fma_mix_f32 %[d], %[s0], %[s1], %[d] op_sel:[0,1,0] op_sel_hi:[1,1,0]"
                    : [d]"+v"(a1) : [s0]"s"(qs[u]), [s1]"v"(rw[u]));
            }
        }
        for (; j < c; ++j) {
            const unsigned q = se[s0 + j];
            const unsigned qs = __builtin_amdgcn_readfirstlane(q);
            const _Float16* rowp = rwb + (size_t)((qs >> 16) & 0xFFFu) * 128;
            const unsigned rwv = *reinterpret_cast<const unsigned*>(rowp + loff);
            asm("v_fma_mix_f32 %[d], %[s0], %[s1], %[d] op_sel:[0,0,0] op_sel_hi:[1,1,0]"
                : [d]"+v"(a0) : [s0]"s"(qs), [s1]"v"(rwv));
            asm("v_fma_mix_f32 %[d], %[s0], %[s1], %[d] op_sel:[0,1,0] op_sel_hi:[1,1,0]"
                : [d]"+v"(a1) : [s0]"s"(qs), [s1]"v"(rwv));
        }
        if (vent < NUMENT) {
            float* op = out + (size_t)vent * 128 + loff;
            float2 sp = *reinterpret_cast<const float2*>(op);  // spill contrib (normally 0)
            float2 o;
            o.x = fmaxf(a0 + sp.x, 0.f);
            o.y = fmaxf(a1 + sp.y, 0.f);
            *reinterpret_cast<float2*>(op) = o;
        }
    }
}

// ---------------------------------------------------------------------------
// Fallback path (ws too small / shape out of range): direct vector scatter.
// ---------------------------------------------------------------------------
__global__ void rwb_f32_kernel(const float* __restrict__ rel, const float* __restrict__ W,
                               const float* __restrict__ b, float* __restrict__ rwb, int R) {
    const int k = blockIdx.x;
    const int n = threadIdx.x;
    __shared__ float relk[128];
    relk[n] = rel[(size_t)k * 128 + n];
    __syncthreads();
    const float4* w4 = reinterpret_cast<const float4*>(W + (size_t)n * 128);
    const float4* r4 = reinterpret_cast<const float4*>(relk);
    float acc = 0.f;
#pragma unroll
    for (int i = 0; i < 32; ++i) {
        float4 a = r4[i], w = w4[i];
        acc += a.x * w.x + a.y * w.y + a.z * w.z + a.w * w.w;
    }
    rwb[(size_t)k * 128 + n] = acc + b[n];
}

__global__ void scatter_vec_kernel(const int* __restrict__ heads, const int* __restrict__ tails,
                                   const int* __restrict__ rels, const float* __restrict__ val,
                                   const float* __restrict__ rwb, float* __restrict__ out,
                                   long long nitems) {
    const long long i = (long long)blockIdx.x * blockDim.x + threadIdx.x;
    if (i >= nitems) return;
    const int e = (int)(i >> 5);
    const int c = (int)(i & 31) * 4;
    const float v = val[e];
    float4 rw = *reinterpret_cast<const float4*>(rwb + (size_t)rels[e] * 128 + c);
    float* pt = out + (size_t)tails[e] * 128 + c;
    float* ph = out + (size_t)heads[e] * 128 + c;
    unsafeAtomicAdd(pt + 0, v * rw.x); unsafeAtomicAdd(pt + 1, v * rw.y);
    unsafeAtomicAdd(pt + 2, v * rw.z); unsafeAtomicAdd(pt + 3, v * rw.w);
    unsafeAtomicAdd(ph + 0, v * rw.x); unsafeAtomicAdd(ph + 1, v * rw.y);
    unsafeAtomicAdd(ph + 2, v * rw.z); unsafeAtomicAdd(ph + 3, v * rw.w);
}

__global__ void relu_kernel(float* __restrict__ out, int n4) {
    const int i = blockIdx.x * blockDim.x + threadIdx.x;
    if (i >= n4) return;
    float4* p = reinterpret_cast<float4*>(out) + i;
    float4 v = *p;
    v.x = fmaxf(v.x, 0.f); v.y = fmaxf(v.y, 0.f);
    v.z = fmaxf(v.z, 0.f); v.w = fmaxf(v.w, 0.f);
    *p = v;
}

// ---------------------------------------------------------------------------
extern "C" void kernel_launch(void* const* d_in, const int* in_sizes, int n_in,
                              void* d_out, int out_size, void* d_ws, size_t ws_size,
                              hipStream_t stream) {
    // inputs: 0 local_entity [B*M] (shape only), 1 heads [E], 2 tails [E],
    //         3 rels [E], 4 val [E], 5 rel_features [R*D], 6 W [D*D], 7 b [D]
    const int* heads = (const int*)d_in[1];
    const int* tails = (const int*)d_in[2];
    const int* rels  = (const int*)d_in[3];
    const float* val  = (const float*)d_in[4];
    const float* relf = (const float*)d_in[5];
    const float* W    = (const float*)d_in[6];
    const float* b    = (const float*)d_in[7];
    float* out = (float*)d_out;

    const int NUMENT = in_sizes[0];          // 16000
    const int E      = in_sizes[1];          // 2,000,000
    const int D      = in_sizes[7];          // 128
    const int R      = in_sizes[5] / D;      // 2000

    const int NB = (NUMENT + EPB - 1) / EPB; // 1000 buckets
    // expected endpoints/bucket = 2E*EPB/NUMENT (=4000, sigma~63);
    // slack mean/16+256 ~ +9.6 sigma at default shape
    const long long mean = (2LL * E * EPB) / (NUMENT > 0 ? NUMENT : 1);
    int CAPB = (int)(mean + mean / 16 + 256);

    const size_t rwb_bytes = (size_t)R * D * sizeof(_Float16);          // 512 KB
    const size_t off_gcnt  = (rwb_bytes + 255) & ~(size_t)255;
    const size_t gcnt_b    = (size_t)NB * sizeof(int);
    const size_t off_slots = (off_gcnt + gcnt_b + 255) & ~(size_t)255;
    const size_t slots_b   = (size_t)NB * CAPB * sizeof(unsigned);      // ~18 MB

    if (NB <= MAXNB && R < 4096 && CAPB <= SORTCAP &&
        ws_size >= off_slots + slots_b) {
        _Float16* rwb   = (_Float16*)d_ws;
        int* gcnt       = (int*)((char*)d_ws + off_gcnt);
        unsigned* slots = (unsigned*)((char*)d_ws + off_slots);

        rwb_row_kernel<<<R, 128, 0, stream>>>(relf, W, b, rwb, R, gcnt, out, NB, NUMENT);
        bin_kernel<<<(E + FPB - 1) / FPB, 1024, 0, stream>>>(
            heads, tails, rels, val, gcnt, slots, rwb, out, E, NB, CAPB);
        gather_kernel<<<NB, 512, 0, stream>>>(slots, gcnt, rwb, out, NUMENT, CAPB);
    } else {
        // fallback: accumulate directly into out (slow but small-ws safe)
        float* rwb = (float*)d_ws;           // R*D fp32 (~1 MB)
        hipMemsetAsync(out, 0, (size_t)out_size * sizeof(float), stream);
        rwb_f32_kernel<<<R, 128, 0, stream>>>(relf, W, b, rwb, R);
        const long long items = (long long)E * 32;
        scatter_vec_kernel<<<(unsigned)((items + 255) / 256), 256, 0, stream>>>(
            heads, tails, rels, val, rwb, out, items);
        relu_kernel<<<(out_size / 4 + 255) / 256, 256, 0, stream>>>(out, out_size / 4);
    }
}